// Round 9
// baseline (268.116 us; speedup 1.0000x reference)
//
#include <hip/hip_runtime.h>
#include <hip/hip_bf16.h>

// Problem constants
#define BATCH 2
#define SEQ   2048
#define EMB   1024
#define NH    16
#define HD    64
#define MROWS (BATCH*SEQ)   // 4096
#define NX    (MROWS*EMB)   // 4194304
#define NW    (EMB*EMB)     // 1048576 = 2^20

using f32x4  = __attribute__((ext_vector_type(4))) float;
using bf16x8 = __attribute__((ext_vector_type(8))) short;

#define GLOBAL_AS(p) ((const __attribute__((address_space(1))) void*)(p))
#define LDS_AS(p)    ((__attribute__((address_space(3))) void*)(p))

#define ROPE_L2 0.4152410118609203f    // log2(10000)/32
#define QSCALE  0.045084220027780106f  // (1/sqrt(E)) * log2(e)

// ---------------------------------------------------------------------------
// Fused f32->bf16 cast of x and the 4 weight matrices (Wq,Wk,Wv stacked).
// ---------------------------------------------------------------------------
__global__ void fused_cast_kernel(const float* __restrict__ x,
                                  const float* __restrict__ Wq,
                                  const float* __restrict__ Wk,
                                  const float* __restrict__ Wv,
                                  const float* __restrict__ Wo,
                                  __hip_bfloat16* __restrict__ xb,
                                  __hip_bfloat16* __restrict__ Wqkvb,
                                  __hip_bfloat16* __restrict__ Wob) {
    size_t i8 = (size_t)(blockIdx.x * 256 + threadIdx.x) * 8;
    const float* src;
    __hip_bfloat16* dst;
    if (i8 < (size_t)NX) {
        src = x + i8;
        dst = xb + i8;
    } else {
        size_t w = i8 - NX;
        int which = (int)(w >> 20);
        size_t local = w & (NW - 1);
        if (which < 3) {
            src = (which == 0 ? Wq : (which == 1 ? Wk : Wv)) + local;
            dst = Wqkvb + w;
        } else {
            src = Wo + local;
            dst = Wob + local;
        }
    }
    float4 a = *(const float4*)(src);
    float4 b = *(const float4*)(src + 4);
    union { uint4 u; ushort s[8]; } o;
    const float* f = (const float*)&a;
#pragma unroll
    for (int j = 0; j < 4; ++j) {
        __hip_bfloat16 h = __float2bfloat16(f[j]);
        o.s[j] = *(ushort*)&h;
    }
    f = (const float*)&b;
#pragma unroll
    for (int j = 0; j < 4; ++j) {
        __hip_bfloat16 h = __float2bfloat16(f[j]);
        o.s[4 + j] = *(ushort*)&h;
    }
    *(uint4*)dst = o.u;
}

// ---------------------------------------------------------------------------
// Fused QKV GEMM: C[M,3072] = A[M,K] * Wqkv[3072,K]^T, routed to Q/K/V.
// 128x128 tile, BK=64, global_load_lds staging. grid (24,32) = 3 blocks/CU.
// ---------------------------------------------------------------------------
__global__ __launch_bounds__(256) void gemm_qkv_kernel(
        const __hip_bfloat16* __restrict__ A,
        const __hip_bfloat16* __restrict__ W,
        __hip_bfloat16* __restrict__ Qo,
        __hip_bfloat16* __restrict__ Ko,
        __hip_bfloat16* __restrict__ Vo, int M, int K) {
    __shared__ __hip_bfloat16 As[128 * 64];
    __shared__ __hip_bfloat16 Bs[128 * 64];

    const int tid  = threadIdx.x;
    const int wave = tid >> 6;
    const int lane = tid & 63;
    const int quad = lane >> 4;
    const int l16  = lane & 15;
    const int m0   = blockIdx.y * 128;
    const int n0   = blockIdx.x * 128;
    const int wm   = (wave >> 1) * 64;
    const int wn   = (wave & 1) * 64;

    f32x4 acc[4][4] = {};

    for (int k0 = 0; k0 < K; k0 += 64) {
#pragma unroll
        for (int it = 0; it < 4; ++it) {
            int flat = (wave * 4 + it) * 64 + lane;
            int row  = flat >> 3;
            int g    = flat & 7;
            const __hip_bfloat16* ga = A + (size_t)(m0 + row) * K + k0 + g * 8;
            const __hip_bfloat16* gb = W + (size_t)(n0 + row) * K + k0 + g * 8;
            __builtin_amdgcn_global_load_lds(GLOBAL_AS(ga),
                LDS_AS(As + (size_t)(wave * 4 + it) * 512), 16, 0, 0);
            __builtin_amdgcn_global_load_lds(GLOBAL_AS(gb),
                LDS_AS(Bs + (size_t)(wave * 4 + it) * 512), 16, 0, 0);
        }
        __syncthreads();

#pragma unroll
        for (int kk = 0; kk < 2; ++kk) {
            bf16x8 af[4], bfr[4];
#pragma unroll
            for (int i = 0; i < 4; ++i) {
                af[i]  = *(const bf16x8*)(&As[(wm + i * 16 + l16) * 64 + (kk * 4 + quad) * 8]);
                bfr[i] = *(const bf16x8*)(&Bs[(wn + i * 16 + l16) * 64 + (kk * 4 + quad) * 8]);
            }
#pragma unroll
            for (int i = 0; i < 4; ++i)
#pragma unroll
                for (int j = 0; j < 4; ++j)
                    acc[i][j] = __builtin_amdgcn_mfma_f32_16x16x32_bf16(
                        af[i], bfr[j], acc[i][j], 0, 0, 0);
        }
        __syncthreads();
    }

    const int tens = n0 >> 10;
    __hip_bfloat16* outp = (tens == 0) ? Qo : ((tens == 1) ? Ko : Vo);
    const int nbase = n0 & 1023;
#pragma unroll
    for (int i = 0; i < 4; ++i)
#pragma unroll
        for (int j = 0; j < 4; ++j) {
            int col  = nbase + wn + j * 16 + l16;
            int row0 = m0 + wm + i * 16 + quad * 4;
#pragma unroll
            for (int rr = 0; rr < 4; ++rr)
                outp[(size_t)(row0 + rr) * EMB + col] = __float2bfloat16(acc[i][j][rr]);
        }
}

// ---------------------------------------------------------------------------
// O-projection GEMM: C[M,N] = A[M,K] * B[N,K]^T, fp32 out.
// 128x64 tile -> grid (16,32) = 512 blocks = 2/CU.
// ---------------------------------------------------------------------------
__global__ __launch_bounds__(256) void gemm_oproj_kernel(
        const __hip_bfloat16* __restrict__ A,
        const __hip_bfloat16* __restrict__ Bm,
        float* __restrict__ C, int M, int N, int K) {
    __shared__ __hip_bfloat16 As[128 * 64];
    __shared__ __hip_bfloat16 Bs[64 * 64];

    const int tid  = threadIdx.x;
    const int wave = tid >> 6;
    const int lane = tid & 63;
    const int quad = lane >> 4;
    const int l16  = lane & 15;
    const int m0   = blockIdx.y * 128;
    const int n0   = blockIdx.x * 64;
    const int wm   = (wave >> 1) * 64;
    const int wn   = (wave & 1) * 32;

    f32x4 acc[4][2] = {};

    for (int k0 = 0; k0 < K; k0 += 64) {
#pragma unroll
        for (int it = 0; it < 4; ++it) {
            int flat = (wave * 4 + it) * 64 + lane;
            int row  = flat >> 3;
            int g    = flat & 7;
            const __hip_bfloat16* ga = A + (size_t)(m0 + row) * K + k0 + g * 8;
            __builtin_amdgcn_global_load_lds(GLOBAL_AS(ga),
                LDS_AS(As + (size_t)(wave * 4 + it) * 512), 16, 0, 0);
        }
#pragma unroll
        for (int it = 0; it < 2; ++it) {
            int flat = (wave * 2 + it) * 64 + lane;
            int row  = flat >> 3;
            int g    = flat & 7;
            const __hip_bfloat16* gb = Bm + (size_t)(n0 + row) * K + k0 + g * 8;
            __builtin_amdgcn_global_load_lds(GLOBAL_AS(gb),
                LDS_AS(Bs + (size_t)(wave * 2 + it) * 512), 16, 0, 0);
        }
        __syncthreads();

#pragma unroll
        for (int kk = 0; kk < 2; ++kk) {
            bf16x8 af[4], bfr[2];
#pragma unroll
            for (int i = 0; i < 4; ++i)
                af[i] = *(const bf16x8*)(&As[(wm + i * 16 + l16) * 64 + (kk * 4 + quad) * 8]);
#pragma unroll
            for (int j = 0; j < 2; ++j)
                bfr[j] = *(const bf16x8*)(&Bs[(wn + j * 16 + l16) * 64 + (kk * 4 + quad) * 8]);
#pragma unroll
            for (int i = 0; i < 4; ++i)
#pragma unroll
                for (int j = 0; j < 2; ++j)
                    acc[i][j] = __builtin_amdgcn_mfma_f32_16x16x32_bf16(
                        af[i], bfr[j], acc[i][j], 0, 0, 0);
        }
        __syncthreads();
    }

#pragma unroll
    for (int i = 0; i < 4; ++i)
#pragma unroll
        for (int j = 0; j < 2; ++j) {
            int col  = n0 + wn + j * 16 + l16;
            int row0 = m0 + wm + i * 16 + quad * 4;
#pragma unroll
            for (int rr = 0; rr < 4; ++rr)
                C[(size_t)(row0 + rr) * N + col] = acc[i][j][rr];
        }
}

// ---------------------------------------------------------------------------
// RoPE in-place on bf16 Q and K (accurate sinf/cosf); Q scaled by QSCALE.
// ---------------------------------------------------------------------------
__global__ void rope_bf16_kernel(__hip_bfloat16* __restrict__ Q,
                                 __hip_bfloat16* __restrict__ K, int n8) {
    int idx = blockIdx.x * blockDim.x + threadIdx.x;
    if (idx >= n8) return;
    int d8 = idx & 7;
    int s  = (idx >> 7) & (SEQ - 1);
    float c[4], sn[4];
#pragma unroll
    for (int j = 0; j < 4; ++j) {
        int i = d8 * 4 + j;
        float inv = exp2f(-(float)i * ROPE_L2);
        float fr  = (float)s * inv;
        c[j]  = cosf(fr);
        sn[j] = sinf(fr);
    }
    size_t base = (size_t)idx * 8;
    uint4 qv = *(uint4*)((char*)Q + base * 2);
    uint4 kv = *(uint4*)((char*)K + base * 2);
    ushort* qe = (ushort*)&qv;
    ushort* ke = (ushort*)&kv;
#pragma unroll
    for (int j = 0; j < 4; ++j) {
        float q1 = __bfloat162float(*(__hip_bfloat16*)&qe[2 * j]);
        float q2 = __bfloat162float(*(__hip_bfloat16*)&qe[2 * j + 1]);
        float o1 = (q1 * c[j] - q2 * sn[j]) * QSCALE;
        float o2 = (q2 * c[j] + q1 * sn[j]) * QSCALE;
        *(__hip_bfloat16*)&qe[2 * j]     = __float2bfloat16(o1);
        *(__hip_bfloat16*)&qe[2 * j + 1] = __float2bfloat16(o2);
        float k1 = __bfloat162float(*(__hip_bfloat16*)&ke[2 * j]);
        float k2 = __bfloat162float(*(__hip_bfloat16*)&ke[2 * j + 1]);
        float p1 = k1 * c[j] - k2 * sn[j];
        float p2 = k2 * c[j] + k1 * sn[j];
        *(__hip_bfloat16*)&ke[2 * j]     = __float2bfloat16(p1);
        *(__hip_bfloat16*)&ke[2 * j + 1] = __float2bfloat16(p2);
    }
    *(uint4*)((char*)Q + base * 2) = qv;
    *(uint4*)((char*)K + base * 2) = kv;
}

__device__ inline uint pack_bf16(float a, float b) {
    __hip_bfloat16 ha = __float2bfloat16(a), hb = __float2bfloat16(b);
    return (uint)*(ushort*)&ha | ((uint)*(ushort*)&hb << 16);
}

// ---------------------------------------------------------------------------
// S^T flash attention (causal), fixed-base exp2 softmax (QSCALE*log2e in Q).
// Computes S^T = K·Q^T (A and B fragment layouts are identical, so operand
// swap is free). C-layout then gives each lane 4 CONSECUTIVE keys of ONE
// q-row (q=l16): P writes collapse to 4 ds_write_b64, l-sum becomes a lane
// scalar (2 shfl reduce). PV (A=P, B=V^T) output layout is unchanged.
// Partition (round-7): grid (48, B*H) = 1536 blocks:
//   bx<32:  qt = 31-(bx>>1), chunk c=bx&1 splits k-range in half
//   bx>=32: qt = 15-(bx-32), single chunk (c=0)
// Single-buffered LDS (25.9 KB -> 6 blocks/CU; 1536 = exactly resident),
// register prefetch, 2 barriers/tile. Partials additive; combine pass divides.
// ---------------------------------------------------------------------------
__global__ __launch_bounds__(256, 6) void attn_mfma_kernel(
        const __hip_bfloat16* __restrict__ Qb,
        const __hip_bfloat16* __restrict__ Kb,
        const __hip_bfloat16* __restrict__ Vb,
        __hip_bfloat16* __restrict__ Opart,
        float* __restrict__ Lpart) {
    const int bx   = blockIdx.x;
    const int bh   = blockIdx.y;
    const int b    = bh >> 4;
    const int h    = bh & (NH - 1);
    const int tid  = threadIdx.x;
    const int wave = tid >> 6;
    const int lane = tid & 63;
    const int quad = lane >> 4;
    const int l16  = lane & 15;

    int qt, c, kLo, kHi;
    if (bx < 32) {
        qt = 31 - (bx >> 1);
        c  = bx & 1;
        int half = (qt + 1) >> 1;
        kLo = c ? half : 0;
        kHi = c ? (qt + 1) : half;
    } else {
        qt = 15 - (bx - 32);
        c  = 0;
        kLo = 0;
        kHi = qt + 1;
    }
    const int wrow = qt * 64 + wave * 16;

    __shared__ __hip_bfloat16 Ks[64 * 64];     // XOR swizzled, key-major
    __shared__ uint VTs[64][33];               // packed V^T pairs
    __shared__ __hip_bfloat16 Ps[4][16 * 72];  // per-wave P (q-row major)

    const int srow0 = tid >> 3;
    const int sg    = tid & 7;
    const int sgp   = sg ^ (srow0 & 7);
    const int vtp   = tid >> 3;

    const __hip_bfloat16* Kbase = Kb + (size_t)b * SEQ * EMB + h * HD;
    const __hip_bfloat16* Vbase = Vb + (size_t)b * SEQ * EMB + h * HD;

    // Q fragments (B operand now; layout identical to A): lane = q-row l16
    bf16x8 qf[2];
    {
        const __hip_bfloat16* qp =
            Qb + (size_t)(b * SEQ + wrow + l16) * EMB + h * HD + quad * 8;
        qf[0] = *(const bf16x8*)(qp);
        qf[1] = *(const bf16x8*)(qp + 32);
    }

    float lsum = 0.0f;       // partial row-sum for q = wrow + l16
    f32x4 of[4] = {};        // O: col d = nb*16+l16, row q = quad*4+r

    // prologue: prefetch first tile into registers
    uint4 kr0, kr1, vr0, vr1;
    {
        const __hip_bfloat16* kp = Kbase + (size_t)(kLo * 64 + srow0) * EMB + sg * 8;
        kr0 = *(const uint4*)(kp);
        kr1 = *(const uint4*)(kp + (size_t)32 * EMB);
        const __hip_bfloat16* vp = Vbase + (size_t)(kLo * 64 + 2 * vtp) * EMB + sg * 8;
        vr0 = *(const uint4*)(vp);
        vr1 = *(const uint4*)(vp + EMB);
    }

    for (int kt = kLo; kt < kHi; ++kt) {
        __syncthreads();                 // all waves done reading prev tile
        *(uint4*)(&Ks[srow0 * 64 + sgp * 8])        = kr0;
        *(uint4*)(&Ks[(srow0 + 32) * 64 + sgp * 8]) = kr1;
        {
            const ushort* lo = (const ushort*)&vr0;
            const ushort* hi = (const ushort*)&vr1;
#pragma unroll
            for (int e = 0; e < 8; ++e)
                VTs[sg * 8 + e][vtp] = (uint)lo[e] | ((uint)hi[e] << 16);
        }
        __syncthreads();                 // tile visible
        if (kt + 1 < kHi) {
            const int tb = (kt + 1) * 64;
            const __hip_bfloat16* kp = Kbase + (size_t)(tb + srow0) * EMB + sg * 8;
            kr0 = *(const uint4*)(kp);
            kr1 = *(const uint4*)(kp + (size_t)32 * EMB);
            const __hip_bfloat16* vp = Vbase + (size_t)(tb + 2 * vtp) * EMB + sg * 8;
            vr0 = *(const uint4*)(vp);
            vr1 = *(const uint4*)(vp + EMB);
        }

        // ---- S^T = K·Q^T: sc[mb] covers keys mb*16.. for q = wrow+l16 ----
        const bool diag = (kt == qt);
        f32x4 sc[4];
#pragma unroll
        for (int mb = 0; mb < 4; ++mb) {
            f32x4 a = {};
            if (!(diag && mb > wave)) {
                int krow = mb * 16 + l16;
#pragma unroll
                for (int kb = 0; kb < 2; ++kb) {
                    int kg = (kb * 4 + quad) ^ (krow & 7);
                    bf16x8 kf = *(const bf16x8*)(&Ks[krow * 64 + kg * 8]);
                    a = __builtin_amdgcn_mfma_f32_16x16x32_bf16(kf, qf[kb], a, 0, 0, 0);
                }
            }
            sc[mb] = a;
        }

        // mask: key = mb*16+quad*4+r  vs  q = wave*16+l16 (local offsets)
        if (diag) {
#pragma unroll
            for (int mb = 0; mb < 4; ++mb)
#pragma unroll
                for (int r = 0; r < 4; ++r)
                    if (mb * 16 + quad * 4 + r > wave * 16 + l16)
                        sc[mb][r] = -16384.0f;
        }

        // ---- p = 2^s ; lane-scalar partial sum ----
#pragma unroll
        for (int mb = 0; mb < 4; ++mb)
#pragma unroll
            for (int r = 0; r < 4; ++r) {
                float pv = exp2f(sc[mb][r]);
                sc[mb][r] = pv;
                lsum += pv;
            }

        // ---- P -> LDS: 4 consecutive keys per lane = one b64 per mb ----
        __hip_bfloat16* ps = &Ps[wave][0];
#pragma unroll
        for (int mb = 0; mb < 4; ++mb) {
            uint2 t;
            t.x = pack_bf16(sc[mb][0], sc[mb][1]);
            t.y = pack_bf16(sc[mb][2], sc[mb][3]);
            *(uint2*)(ps + l16 * 72 + mb * 16 + quad * 4) = t;
        }
        __asm__ volatile("s_waitcnt lgkmcnt(0)" ::: "memory");
        bf16x8 pf[2];
        pf[0] = *(const bf16x8*)(ps + l16 * 72 + quad * 8);
        pf[1] = *(const bf16x8*)(ps + l16 * 72 + 32 + quad * 8);

        // ---- O += P V ----
#pragma unroll
        for (int nb = 0; nb < 4; ++nb) {
            const __hip_bfloat16* vrow = (const __hip_bfloat16*)&VTs[nb * 16 + l16][0];
#pragma unroll
            for (int kb2 = 0; kb2 < 2; ++kb2) {
                bf16x8 vf = *(const bf16x8*)(vrow + kb2 * 32 + quad * 8);
                of[nb] = __builtin_amdgcn_mfma_f32_16x16x32_bf16(pf[kb2], vf, of[nb], 0, 0, 0);
            }
        }
    }

    // ---- partial epilogue: reduce l over quads, store raw O + l ----
    lsum += __shfl_xor(lsum, 16);
    lsum += __shfl_xor(lsum, 32);
    const size_t slot = (size_t)(c * 32 + bh);
    if (quad == 0)
        Lpart[slot * SEQ + wrow + l16] = lsum;
#pragma unroll
    for (int nb = 0; nb < 4; ++nb)
#pragma unroll
        for (int r = 0; r < 4; ++r)
            Opart[(slot * SEQ + wrow + quad * 4 + r) * HD + nb * 16 + l16] =
                __float2bfloat16(of[nb][r]);
}

// ---------------------------------------------------------------------------
// Combine partials: out = (O0 + O1?) / (l0 + l1?). Slot 1 only for qt >= 16.
// ---------------------------------------------------------------------------
__global__ void combine_kernel(const __hip_bfloat16* __restrict__ Opart,
                               const float* __restrict__ Lpart,
                               __hip_bfloat16* __restrict__ Attnb) {
    int idx = blockIdx.x * 256 + threadIdx.x;   // 524288 total
    int d8 = idx & 7;
    int s  = (idx >> 3) & (SEQ - 1);
    int bh = idx >> 14;
    int b  = bh >> 4;
    int h  = bh & (NH - 1);
    int qt = s >> 6;

    size_t base0 = ((size_t)bh * SEQ + s) * HD + d8 * 8;
    bf16x8 o0 = *(const bf16x8*)(Opart + base0);
    float l = Lpart[(size_t)bh * SEQ + s];
    float acc[8];
#pragma unroll
    for (int j = 0; j < 8; ++j)
        acc[j] = __uint_as_float(((uint)(ushort)o0[j]) << 16);
    if (qt >= 16) {
        size_t base1 = ((size_t)(32 + bh) * SEQ + s) * HD + d8 * 8;
        bf16x8 o1 = *(const bf16x8*)(Opart + base1);
        l += Lpart[(size_t)(32 + bh) * SEQ + s];
#pragma unroll
        for (int j = 0; j < 8; ++j)
            acc[j] += __uint_as_float(((uint)(ushort)o1[j]) << 16);
    }
    float inv = 1.0f / l;
    union { uint4 u; ushort w[8]; } o;
#pragma unroll
    for (int j = 0; j < 8; ++j) {
        __hip_bfloat16 hv = __float2bfloat16(acc[j] * inv);
        o.w[j] = *(ushort*)&hv;
    }
    *(uint4*)(Attnb + ((size_t)(b * SEQ + s) * EMB) + h * HD + d8 * 8) = o.u;
}

// ---------------------------------------------------------------------------
extern "C" void kernel_launch(void* const* d_in, const int* in_sizes, int n_in,
                              void* d_out, int out_size, void* d_ws, size_t ws_size,
                              hipStream_t stream) {
    const float* x  = (const float*)d_in[0];
    const float* Wq = (const float*)d_in[1];
    const float* Wk = (const float*)d_in[2];
    const float* Wv = (const float*)d_in[3];
    const float* Wo = (const float*)d_in[4];
    float* out = (float*)d_out;

    char* ws = (char*)d_ws;
    size_t off = 0;
    auto alloc = [&](size_t bytes) -> void* {
        void* p = ws + off;
        off += (bytes + 255) & ~(size_t)255;
        return p;
    };

    __hip_bfloat16* xb    = (__hip_bfloat16*)alloc((size_t)NX * 2);
    __hip_bfloat16* Wqkvb = (__hip_bfloat16*)alloc((size_t)NW * 3 * 2);
    __hip_bfloat16* Wob   = (__hip_bfloat16*)alloc((size_t)NW * 2);
    __hip_bfloat16* Qbuf  = (__hip_bfloat16*)alloc((size_t)NX * 2);
    __hip_bfloat16* Kbuf  = (__hip_bfloat16*)alloc((size_t)NX * 2);
    __hip_bfloat16* Vbuf  = (__hip_bfloat16*)alloc((size_t)NX * 2);
    __hip_bfloat16* Attnb = (__hip_bfloat16*)alloc((size_t)NX * 2);
    __hip_bfloat16* Opart = (__hip_bfloat16*)alloc((size_t)2 * 32 * SEQ * HD * 2);
    float*          Lpart = (float*)alloc((size_t)2 * 32 * SEQ * 4);

    // fused casts
    fused_cast_kernel<<<(NX + 4 * NW) / (256 * 8), 256, 0, stream>>>(
        x, Wq, Wk, Wv, Wo, xb, Wqkvb, Wob);

    // fused QKV projection
    dim3 qgrid(24, MROWS / 128);
    gemm_qkv_kernel<<<qgrid, 256, 0, stream>>>(xb, Wqkvb, Qbuf, Kbuf, Vbuf,
                                               MROWS, EMB);

    // RoPE in-place (+ QSCALE fold into Q)
    const int n8 = NX / 8;
    rope_bf16_kernel<<<n8 / 256, 256, 0, stream>>>(Qbuf, Kbuf, n8);

    // S^T flash attention -> partials (1536 blocks, 6/CU, single pass)
    dim3 agrid(48, BATCH * NH);
    attn_mfma_kernel<<<agrid, 256, 0, stream>>>(Qbuf, Kbuf, Vbuf, Opart, Lpart);

    // combine partials -> Attnb
    combine_kernel<<<(32 * SEQ * 8) / 256, 256, 0, stream>>>(Opart, Lpart, Attnb);

    // output projection -> fp32 d_out (128x64 tiles, 512 blocks)
    dim3 ggrid(EMB / 64, MROWS / 128);
    gemm_oproj_kernel<<<ggrid, 256, 0, stream>>>(Attnb, Wob, out, MROWS, EMB, EMB);
}

// Round 10
// 245.583 us; speedup vs baseline: 1.0918x; 1.0918x over previous
//
#include <hip/hip_runtime.h>
#include <hip/hip_bf16.h>

// Problem constants
#define BATCH 2
#define SEQ   2048
#define EMB   1024
#define NH    16
#define HD    64
#define MROWS (BATCH*SEQ)   // 4096
#define NX    (MROWS*EMB)   // 4194304
#define NW    (EMB*EMB)     // 1048576 = 2^20

using f32x4  = __attribute__((ext_vector_type(4))) float;
using bf16x8 = __attribute__((ext_vector_type(8))) short;

#define GLOBAL_AS(p) ((const __attribute__((address_space(1))) void*)(p))
#define LDS_AS(p)    ((__attribute__((address_space(3))) void*)(p))

#define ROPE_L2 0.4152410118609203f    // log2(10000)/32
#define QSCALE  0.045084220027780106f  // (1/sqrt(E)) * log2(e)

// ---------------------------------------------------------------------------
// Fused f32->bf16 cast of x and the 4 weight matrices (Wq,Wk,Wv stacked).
// ---------------------------------------------------------------------------
__global__ void fused_cast_kernel(const float* __restrict__ x,
                                  const float* __restrict__ Wq,
                                  const float* __restrict__ Wk,
                                  const float* __restrict__ Wv,
                                  const float* __restrict__ Wo,
                                  __hip_bfloat16* __restrict__ xb,
                                  __hip_bfloat16* __restrict__ Wqkvb,
                                  __hip_bfloat16* __restrict__ Wob) {
    size_t i8 = (size_t)(blockIdx.x * 256 + threadIdx.x) * 8;
    const float* src;
    __hip_bfloat16* dst;
    if (i8 < (size_t)NX) {
        src = x + i8;
        dst = xb + i8;
    } else {
        size_t w = i8 - NX;
        int which = (int)(w >> 20);
        size_t local = w & (NW - 1);
        if (which < 3) {
            src = (which == 0 ? Wq : (which == 1 ? Wk : Wv)) + local;
            dst = Wqkvb + w;
        } else {
            src = Wo + local;
            dst = Wob + local;
        }
    }
    float4 a = *(const float4*)(src);
    float4 b = *(const float4*)(src + 4);
    union { uint4 u; ushort s[8]; } o;
    const float* f = (const float*)&a;
#pragma unroll
    for (int j = 0; j < 4; ++j) {
        __hip_bfloat16 h = __float2bfloat16(f[j]);
        o.s[j] = *(ushort*)&h;
    }
    f = (const float*)&b;
#pragma unroll
    for (int j = 0; j < 4; ++j) {
        __hip_bfloat16 h = __float2bfloat16(f[j]);
        o.s[4 + j] = *(ushort*)&h;
    }
    *(uint4*)dst = o.u;
}

// ---------------------------------------------------------------------------
// Fused QKV GEMM: C[M,3072] = A[M,K] * Wqkv[3072,K]^T, routed to Q/K/V.
// 128x128 tile, BK=64, global_load_lds staging. grid (24,32) = 3 blocks/CU.
// ---------------------------------------------------------------------------
__global__ __launch_bounds__(256) void gemm_qkv_kernel(
        const __hip_bfloat16* __restrict__ A,
        const __hip_bfloat16* __restrict__ W,
        __hip_bfloat16* __restrict__ Qo,
        __hip_bfloat16* __restrict__ Ko,
        __hip_bfloat16* __restrict__ Vo, int M, int K) {
    __shared__ __hip_bfloat16 As[128 * 64];
    __shared__ __hip_bfloat16 Bs[128 * 64];

    const int tid  = threadIdx.x;
    const int wave = tid >> 6;
    const int lane = tid & 63;
    const int quad = lane >> 4;
    const int l16  = lane & 15;
    const int m0   = blockIdx.y * 128;
    const int n0   = blockIdx.x * 128;
    const int wm   = (wave >> 1) * 64;
    const int wn   = (wave & 1) * 64;

    f32x4 acc[4][4] = {};

    for (int k0 = 0; k0 < K; k0 += 64) {
#pragma unroll
        for (int it = 0; it < 4; ++it) {
            int flat = (wave * 4 + it) * 64 + lane;
            int row  = flat >> 3;
            int g    = flat & 7;
            const __hip_bfloat16* ga = A + (size_t)(m0 + row) * K + k0 + g * 8;
            const __hip_bfloat16* gb = W + (size_t)(n0 + row) * K + k0 + g * 8;
            __builtin_amdgcn_global_load_lds(GLOBAL_AS(ga),
                LDS_AS(As + (size_t)(wave * 4 + it) * 512), 16, 0, 0);
            __builtin_amdgcn_global_load_lds(GLOBAL_AS(gb),
                LDS_AS(Bs + (size_t)(wave * 4 + it) * 512), 16, 0, 0);
        }
        __syncthreads();

#pragma unroll
        for (int kk = 0; kk < 2; ++kk) {
            bf16x8 af[4], bfr[4];
#pragma unroll
            for (int i = 0; i < 4; ++i) {
                af[i]  = *(const bf16x8*)(&As[(wm + i * 16 + l16) * 64 + (kk * 4 + quad) * 8]);
                bfr[i] = *(const bf16x8*)(&Bs[(wn + i * 16 + l16) * 64 + (kk * 4 + quad) * 8]);
            }
#pragma unroll
            for (int i = 0; i < 4; ++i)
#pragma unroll
                for (int j = 0; j < 4; ++j)
                    acc[i][j] = __builtin_amdgcn_mfma_f32_16x16x32_bf16(
                        af[i], bfr[j], acc[i][j], 0, 0, 0);
        }
        __syncthreads();
    }

    const int tens = n0 >> 10;
    __hip_bfloat16* outp = (tens == 0) ? Qo : ((tens == 1) ? Ko : Vo);
    const int nbase = n0 & 1023;
#pragma unroll
    for (int i = 0; i < 4; ++i)
#pragma unroll
        for (int j = 0; j < 4; ++j) {
            int col  = nbase + wn + j * 16 + l16;
            int row0 = m0 + wm + i * 16 + quad * 4;
#pragma unroll
            for (int rr = 0; rr < 4; ++rr)
                outp[(size_t)(row0 + rr) * EMB + col] = __float2bfloat16(acc[i][j][rr]);
        }
}

// ---------------------------------------------------------------------------
// O-projection GEMM: C[M,N] = A[M,K] * B[N,K]^T, fp32 out.
// 128x64 tile -> grid (16,32) = 512 blocks = 2/CU.
// ---------------------------------------------------------------------------
__global__ __launch_bounds__(256) void gemm_oproj_kernel(
        const __hip_bfloat16* __restrict__ A,
        const __hip_bfloat16* __restrict__ Bm,
        float* __restrict__ C, int M, int N, int K) {
    __shared__ __hip_bfloat16 As[128 * 64];
    __shared__ __hip_bfloat16 Bs[64 * 64];

    const int tid  = threadIdx.x;
    const int wave = tid >> 6;
    const int lane = tid & 63;
    const int quad = lane >> 4;
    const int l16  = lane & 15;
    const int m0   = blockIdx.y * 128;
    const int n0   = blockIdx.x * 64;
    const int wm   = (wave >> 1) * 64;
    const int wn   = (wave & 1) * 32;

    f32x4 acc[4][2] = {};

    for (int k0 = 0; k0 < K; k0 += 64) {
#pragma unroll
        for (int it = 0; it < 4; ++it) {
            int flat = (wave * 4 + it) * 64 + lane;
            int row  = flat >> 3;
            int g    = flat & 7;
            const __hip_bfloat16* ga = A + (size_t)(m0 + row) * K + k0 + g * 8;
            __builtin_amdgcn_global_load_lds(GLOBAL_AS(ga),
                LDS_AS(As + (size_t)(wave * 4 + it) * 512), 16, 0, 0);
        }
#pragma unroll
        for (int it = 0; it < 2; ++it) {
            int flat = (wave * 2 + it) * 64 + lane;
            int row  = flat >> 3;
            int g    = flat & 7;
            const __hip_bfloat16* gb = Bm + (size_t)(n0 + row) * K + k0 + g * 8;
            __builtin_amdgcn_global_load_lds(GLOBAL_AS(gb),
                LDS_AS(Bs + (size_t)(wave * 2 + it) * 512), 16, 0, 0);
        }
        __syncthreads();

#pragma unroll
        for (int kk = 0; kk < 2; ++kk) {
            bf16x8 af[4], bfr[2];
#pragma unroll
            for (int i = 0; i < 4; ++i)
                af[i] = *(const bf16x8*)(&As[(wm + i * 16 + l16) * 64 + (kk * 4 + quad) * 8]);
#pragma unroll
            for (int j = 0; j < 2; ++j)
                bfr[j] = *(const bf16x8*)(&Bs[(wn + j * 16 + l16) * 64 + (kk * 4 + quad) * 8]);
#pragma unroll
            for (int i = 0; i < 4; ++i)
#pragma unroll
                for (int j = 0; j < 2; ++j)
                    acc[i][j] = __builtin_amdgcn_mfma_f32_16x16x32_bf16(
                        af[i], bfr[j], acc[i][j], 0, 0, 0);
        }
        __syncthreads();
    }

#pragma unroll
    for (int i = 0; i < 4; ++i)
#pragma unroll
        for (int j = 0; j < 2; ++j) {
            int col  = n0 + wn + j * 16 + l16;
            int row0 = m0 + wm + i * 16 + quad * 4;
#pragma unroll
            for (int rr = 0; rr < 4; ++rr)
                C[(size_t)(row0 + rr) * N + col] = acc[i][j][rr];
        }
}

// ---------------------------------------------------------------------------
// RoPE in-place on bf16 Q and K (accurate sinf/cosf); Q scaled by QSCALE.
// ---------------------------------------------------------------------------
__global__ void rope_bf16_kernel(__hip_bfloat16* __restrict__ Q,
                                 __hip_bfloat16* __restrict__ K, int n8) {
    int idx = blockIdx.x * blockDim.x + threadIdx.x;
    if (idx >= n8) return;
    int d8 = idx & 7;
    int s  = (idx >> 7) & (SEQ - 1);
    float c[4], sn[4];
#pragma unroll
    for (int j = 0; j < 4; ++j) {
        int i = d8 * 4 + j;
        float inv = exp2f(-(float)i * ROPE_L2);
        float fr  = (float)s * inv;
        c[j]  = cosf(fr);
        sn[j] = sinf(fr);
    }
    size_t base = (size_t)idx * 8;
    uint4 qv = *(uint4*)((char*)Q + base * 2);
    uint4 kv = *(uint4*)((char*)K + base * 2);
    ushort* qe = (ushort*)&qv;
    ushort* ke = (ushort*)&kv;
#pragma unroll
    for (int j = 0; j < 4; ++j) {
        float q1 = __bfloat162float(*(__hip_bfloat16*)&qe[2 * j]);
        float q2 = __bfloat162float(*(__hip_bfloat16*)&qe[2 * j + 1]);
        float o1 = (q1 * c[j] - q2 * sn[j]) * QSCALE;
        float o2 = (q2 * c[j] + q1 * sn[j]) * QSCALE;
        *(__hip_bfloat16*)&qe[2 * j]     = __float2bfloat16(o1);
        *(__hip_bfloat16*)&qe[2 * j + 1] = __float2bfloat16(o2);
        float k1 = __bfloat162float(*(__hip_bfloat16*)&ke[2 * j]);
        float k2 = __bfloat162float(*(__hip_bfloat16*)&ke[2 * j + 1]);
        float p1 = k1 * c[j] - k2 * sn[j];
        float p2 = k2 * c[j] + k1 * sn[j];
        *(__hip_bfloat16*)&ke[2 * j]     = __float2bfloat16(p1);
        *(__hip_bfloat16*)&ke[2 * j + 1] = __float2bfloat16(p2);
    }
    *(uint4*)((char*)Q + base * 2) = qv;
    *(uint4*)((char*)K + base * 2) = kv;
}

__device__ inline uint pack_bf16(float a, float b) {
    __hip_bfloat16 ha = __float2bfloat16(a), hb = __float2bfloat16(b);
    return (uint)*(ushort*)&ha | ((uint)*(ushort*)&hb << 16);
}

// ---------------------------------------------------------------------------
// S^T flash attention (causal), fixed-base exp2 softmax (QSCALE*log2e in Q).
// S^T = K·Q^T (operand swap is free: A and B fragment layouts identical).
// Lane then owns 4 consecutive keys of one q-row: P -> LDS = 4 ds_write_b64;
// l is a lane scalar (2 shfl reduce at segment end).
// Partition (round-8, balanced, fused final): grid (32, B*H) = 1024 blocks:
//   bx<16  (A, p=bx):    q-tile 31-p, k-tiles [0,17)       -> partial slot 0
//   bx>=16 (B, p=bx-16): q-tile 31-p, k-tiles [17, 31-p]   -> partial slot 1
//                        then q-tile p, k-tiles [0, p]     -> FINAL write
// Single-buffered LDS (25.9 KB), register prefetch, 2 barriers/tile.
// NO min-waves launch bound: VGPR ~60 keeps the prefetch set live (round 9's
// (256,6) forced VGPR=40 and killed the prefetch -> 16% regression).
// ---------------------------------------------------------------------------
__global__ __launch_bounds__(256) void attn_mfma_kernel(
        const __hip_bfloat16* __restrict__ Qb,
        const __hip_bfloat16* __restrict__ Kb,
        const __hip_bfloat16* __restrict__ Vb,
        __hip_bfloat16* __restrict__ Attnb,
        __hip_bfloat16* __restrict__ Opart,
        float* __restrict__ Lpart) {
    const int bx   = blockIdx.x;
    const int bh   = blockIdx.y;
    const int b    = bh >> 4;
    const int h    = bh & (NH - 1);
    const int tid  = threadIdx.x;
    const int wave = tid >> 6;
    const int lane = tid & 63;
    const int quad = lane >> 4;
    const int l16  = lane & 15;

    __shared__ __hip_bfloat16 Ks[64 * 64];     // XOR swizzled, key-major
    __shared__ uint VTs[64][33];               // packed V^T pairs
    __shared__ __hip_bfloat16 Ps[4][16 * 72];  // per-wave P (q-row major)

    const int srow0 = tid >> 3;
    const int sg    = tid & 7;
    const int sgp   = sg ^ (srow0 & 7);
    const int vtp   = tid >> 3;

    const __hip_bfloat16* Kbase = Kb + (size_t)b * SEQ * EMB + h * HD;
    const __hip_bfloat16* Vbase = Vb + (size_t)b * SEQ * EMB + h * HD;

    const bool isA = (bx < 16);
    const int p   = isA ? bx : bx - 16;
    const int q0  = 31 - p;
    const int k00 = isA ? 0 : 17;
    const int n0s = isA ? 17 : (15 - p);
    const int q1  = p;
    const int n1s = isA ? 0 : (p + 1);

    for (int s = 0; s < 2; ++s) {
        const int qt = s ? q1 : q0;
        const int k0 = s ? 0 : k00;
        const int nt = s ? n1s : n0s;
        if (nt <= 0) continue;               // block-uniform
        const bool finalSeg = (!isA && s == 1);
        const int wrow = qt * 64 + wave * 16;

        // Q fragments (B operand; layout identical to A): lane = q-row l16
        bf16x8 qf[2];
        {
            const __hip_bfloat16* qp =
                Qb + (size_t)(b * SEQ + wrow + l16) * EMB + h * HD + quad * 8;
            qf[0] = *(const bf16x8*)(qp);
            qf[1] = *(const bf16x8*)(qp + 32);
        }

        float lsum = 0.0f;       // partial row-sum for q = wrow + l16
        f32x4 of[4] = {};        // O: col d = nb*16+l16, row q = quad*4+r

        // prologue: prefetch first tile into registers
        uint4 kr0, kr1, vr0, vr1;
        {
            const __hip_bfloat16* kp = Kbase + (size_t)(k0 * 64 + srow0) * EMB + sg * 8;
            kr0 = *(const uint4*)(kp);
            kr1 = *(const uint4*)(kp + (size_t)32 * EMB);
            const __hip_bfloat16* vp = Vbase + (size_t)(k0 * 64 + 2 * vtp) * EMB + sg * 8;
            vr0 = *(const uint4*)(vp);
            vr1 = *(const uint4*)(vp + EMB);
        }

        for (int i = 0; i < nt; ++i) {
            const int kt = k0 + i;
            __syncthreads();                 // all waves done reading prev tile
            *(uint4*)(&Ks[srow0 * 64 + sgp * 8])        = kr0;
            *(uint4*)(&Ks[(srow0 + 32) * 64 + sgp * 8]) = kr1;
            {
                const ushort* lo = (const ushort*)&vr0;
                const ushort* hi = (const ushort*)&vr1;
#pragma unroll
                for (int e = 0; e < 8; ++e)
                    VTs[sg * 8 + e][vtp] = (uint)lo[e] | ((uint)hi[e] << 16);
            }
            __syncthreads();                 // tile visible
            if (i + 1 < nt) {
                const int tb = (kt + 1) * 64;
                const __hip_bfloat16* kp = Kbase + (size_t)(tb + srow0) * EMB + sg * 8;
                kr0 = *(const uint4*)(kp);
                kr1 = *(const uint4*)(kp + (size_t)32 * EMB);
                const __hip_bfloat16* vp = Vbase + (size_t)(tb + 2 * vtp) * EMB + sg * 8;
                vr0 = *(const uint4*)(vp);
                vr1 = *(const uint4*)(vp + EMB);
            }

            // ---- S^T = K·Q^T: sc[mb] covers keys mb*16.. for q = wrow+l16 ----
            const bool diag = (kt == qt);
            f32x4 sc[4];
#pragma unroll
            for (int mb = 0; mb < 4; ++mb) {
                f32x4 a = {};
                if (!(diag && mb > wave)) {
                    int krow = mb * 16 + l16;
#pragma unroll
                    for (int kb = 0; kb < 2; ++kb) {
                        int kg = (kb * 4 + quad) ^ (krow & 7);
                        bf16x8 kf = *(const bf16x8*)(&Ks[krow * 64 + kg * 8]);
                        a = __builtin_amdgcn_mfma_f32_16x16x32_bf16(kf, qf[kb], a, 0, 0, 0);
                    }
                }
                sc[mb] = a;
            }

            // mask: key = mb*16+quad*4+r  vs  q = wave*16+l16 (local offsets)
            if (diag) {
#pragma unroll
                for (int mb = 0; mb < 4; ++mb)
#pragma unroll
                    for (int r = 0; r < 4; ++r)
                        if (mb * 16 + quad * 4 + r > wave * 16 + l16)
                            sc[mb][r] = -16384.0f;
            }

            // ---- p = 2^s ; lane-scalar partial sum ----
#pragma unroll
            for (int mb = 0; mb < 4; ++mb)
#pragma unroll
                for (int r = 0; r < 4; ++r) {
                    float pv = exp2f(sc[mb][r]);
                    sc[mb][r] = pv;
                    lsum += pv;
                }

            // ---- P -> LDS: 4 consecutive keys per lane = one b64 per mb ----
            __hip_bfloat16* ps = &Ps[wave][0];
#pragma unroll
            for (int mb = 0; mb < 4; ++mb) {
                uint2 t;
                t.x = pack_bf16(sc[mb][0], sc[mb][1]);
                t.y = pack_bf16(sc[mb][2], sc[mb][3]);
                *(uint2*)(ps + l16 * 72 + mb * 16 + quad * 4) = t;
            }
            __asm__ volatile("s_waitcnt lgkmcnt(0)" ::: "memory");
            bf16x8 pf[2];
            pf[0] = *(const bf16x8*)(ps + l16 * 72 + quad * 8);
            pf[1] = *(const bf16x8*)(ps + l16 * 72 + 32 + quad * 8);

            // ---- O += P V ----
#pragma unroll
            for (int nb = 0; nb < 4; ++nb) {
                const __hip_bfloat16* vrow = (const __hip_bfloat16*)&VTs[nb * 16 + l16][0];
#pragma unroll
                for (int kb2 = 0; kb2 < 2; ++kb2) {
                    bf16x8 vf = *(const bf16x8*)(vrow + kb2 * 32 + quad * 8);
                    of[nb] = __builtin_amdgcn_mfma_f32_16x16x32_bf16(pf[kb2], vf, of[nb], 0, 0, 0);
                }
            }
        }

        // ---- segment epilogue ----
        lsum += __shfl_xor(lsum, 16);
        lsum += __shfl_xor(lsum, 32);        // all quads hold total for q=l16
        const int rl0 = quad * 4;            // local output row base within wave tile
        if (finalSeg) {
            float linv[4];
#pragma unroll
            for (int r = 0; r < 4; ++r)
                linv[r] = 1.0f / __shfl(lsum, rl0 + r);   // lane rl0+r holds row rl0+r
#pragma unroll
            for (int nb = 0; nb < 4; ++nb)
#pragma unroll
                for (int r = 0; r < 4; ++r) {
                    float v = of[nb][r] * linv[r];
                    Attnb[(size_t)(b * SEQ + wrow + rl0 + r) * EMB + h * HD + nb * 16 + l16] =
                        __float2bfloat16(v);
                }
        } else {
            const int slot = isA ? 0 : 1;
            const size_t lbase = ((size_t)slot * 32 + bh) * SEQ + wrow;
            if (quad == 0)
                Lpart[lbase + l16] = lsum;
#pragma unroll
            for (int nb = 0; nb < 4; ++nb)
#pragma unroll
                for (int r = 0; r < 4; ++r)
                    Opart[(lbase + rl0 + r) * HD + nb * 16 + l16] =
                        __float2bfloat16(of[nb][r]);
        }
    }
}

// ---------------------------------------------------------------------------
// Combine partials for heavy rows (s >= 1024, qt 16..31):
// out = (O0 + O1?) / (l0 + l1?). Slot 1 exists only for qt >= 17.
// ---------------------------------------------------------------------------
__global__ void combine_kernel(const __hip_bfloat16* __restrict__ Opart,
                               const float* __restrict__ Lpart,
                               __hip_bfloat16* __restrict__ Attnb) {
    int idx = blockIdx.x * 256 + threadIdx.x;   // 262144 total
    int d8 = idx & 7;
    int s  = 1024 + ((idx >> 3) & 1023);        // heavy rows only
    int bh = idx >> 13;
    int b  = bh >> 4;
    int h  = bh & (NH - 1);
    int qt = s >> 6;                            // 16..31

    size_t base0 = ((size_t)bh * SEQ + s) * HD + d8 * 8;
    bf16x8 o0 = *(const bf16x8*)(Opart + base0);
    float l = Lpart[(size_t)bh * SEQ + s];
    float acc[8];
#pragma unroll
    for (int j = 0; j < 8; ++j)
        acc[j] = __uint_as_float(((uint)(ushort)o0[j]) << 16);
    if (qt >= 17) {
        size_t base1 = ((size_t)(32 + bh) * SEQ + s) * HD + d8 * 8;
        bf16x8 o1 = *(const bf16x8*)(Opart + base1);
        l += Lpart[(size_t)(32 + bh) * SEQ + s];
#pragma unroll
        for (int j = 0; j < 8; ++j)
            acc[j] += __uint_as_float(((uint)(ushort)o1[j]) << 16);
    }
    float inv = 1.0f / l;
    union { uint4 u; ushort w[8]; } o;
#pragma unroll
    for (int j = 0; j < 8; ++j) {
        __hip_bfloat16 hv = __float2bfloat16(acc[j] * inv);
        o.w[j] = *(ushort*)&hv;
    }
    *(uint4*)(Attnb + ((size_t)(b * SEQ + s) * EMB) + h * HD + d8 * 8) = o.u;
}

// ---------------------------------------------------------------------------
extern "C" void kernel_launch(void* const* d_in, const int* in_sizes, int n_in,
                              void* d_out, int out_size, void* d_ws, size_t ws_size,
                              hipStream_t stream) {
    const float* x  = (const float*)d_in[0];
    const float* Wq = (const float*)d_in[1];
    const float* Wk = (const float*)d_in[2];
    const float* Wv = (const float*)d_in[3];
    const float* Wo = (const float*)d_in[4];
    float* out = (float*)d_out;

    char* ws = (char*)d_ws;
    size_t off = 0;
    auto alloc = [&](size_t bytes) -> void* {
        void* p = ws + off;
        off += (bytes + 255) & ~(size_t)255;
        return p;
    };

    __hip_bfloat16* xb    = (__hip_bfloat16*)alloc((size_t)NX * 2);
    __hip_bfloat16* Wqkvb = (__hip_bfloat16*)alloc((size_t)NW * 3 * 2);
    __hip_bfloat16* Wob   = (__hip_bfloat16*)alloc((size_t)NW * 2);
    __hip_bfloat16* Qbuf  = (__hip_bfloat16*)alloc((size_t)NX * 2);
    __hip_bfloat16* Kbuf  = (__hip_bfloat16*)alloc((size_t)NX * 2);
    __hip_bfloat16* Vbuf  = (__hip_bfloat16*)alloc((size_t)NX * 2);
    __hip_bfloat16* Attnb = (__hip_bfloat16*)alloc((size_t)NX * 2);
    __hip_bfloat16* Opart = (__hip_bfloat16*)alloc((size_t)2 * 32 * SEQ * HD * 2);
    float*          Lpart = (float*)alloc((size_t)2 * 32 * SEQ * 4);

    // fused casts
    fused_cast_kernel<<<(NX + 4 * NW) / (256 * 8), 256, 0, stream>>>(
        x, Wq, Wk, Wv, Wo, xb, Wqkvb, Wob);

    // fused QKV projection
    dim3 qgrid(24, MROWS / 128);
    gemm_qkv_kernel<<<qgrid, 256, 0, stream>>>(xb, Wqkvb, Qbuf, Kbuf, Vbuf,
                                               MROWS, EMB);

    // RoPE in-place (+ QSCALE fold into Q)
    const int n8 = NX / 8;
    rope_bf16_kernel<<<n8 / 256, 256, 0, stream>>>(Qbuf, Kbuf, n8);

    // S^T flash attention, balanced 2-way split + fused final write
    dim3 agrid(32, BATCH * NH);
    attn_mfma_kernel<<<agrid, 256, 0, stream>>>(Qbuf, Kbuf, Vbuf, Attnb,
                                                Opart, Lpart);

    // combine partials for heavy q-tiles
    combine_kernel<<<(32 * 1024 * 8) / 256, 256, 0, stream>>>(Opart, Lpart, Attnb);

    // output projection -> fp32 d_out (128x64 tiles, 512 blocks)
    dim3 ggrid(EMB / 64, MROWS / 128);
    gemm_oproj_kernel<<<ggrid, 256, 0, stream>>>(Attnb, Wob, out, MROWS, EMB, EMB);
}